// Round 4
// baseline (1239.216 us; speedup 1.0000x reference)
//
#include <hip/hip_runtime.h>

// CapsNet dynamic routing via bf16 MFMA (v_mfma_f32_32x32x16_bf16).
// Shapes: x[64][2048][16], kernel[2048][32][16][32], out V[64][32][32], fp32 in/out.
//
// Round-4 structure: 1024-thr blocks (16 waves), wave w owns d in {2w,2w+1}.
// Per n: 2 MFMAs -> in-reg dot partials -> LDS atomic-add Ds[32][32] ->
// no-max softmax (in-wave over j) -> recompute 2 MFMAs -> S-accum.
// 2 barriers per 2-n pair. reduce_squash split into 2 coalesced stages.

#define NIN   2048
#define DIN   16
#define NOUT  32
#define DOUT  32
#define NTILE 8
#define NB    (NIN/NTILE)   // 256 n-tiles per batch-half

typedef __attribute__((ext_vector_type(8)))  short s16x8;
typedef __attribute__((ext_vector_type(16))) float f32x16;

// ws float offsets
#define WS_BLOG   0                        // 64*2048*32        = 4194304 f
#define WS_SPART  4194304                  // 512 * 32768       = 16777216 f
#define WS_SPART2 20971520                 // 16 * 65536        = 1048576 f
#define WS_V      22020096                 // 65536 f
#define WS_KTF    22085632                 // 2048*32*64*8 bf16 = 16777216 f-equiv
#define WS_XTF    38862848                 // 2*2048*64*8 bf16  = 1048576 f-equiv
// total ~160 MB

__device__ __forceinline__ unsigned short f2bf(float f) {
  unsigned u = __float_as_uint(f);
  u = (u + 0x7fffu + ((u >> 16) & 1u)) >> 16;
  return (unsigned short)u;
}

// Repack kernel[n][j][k][d] fp32 -> Ktf[n][d][lane][i] bf16 via LDS transpose.
// B-fragment convention: col j = lane&31, k = (lane>>5)*8 + i  (same as A's).
__global__ __launch_bounds__(256) void conv_k(const float* __restrict__ Kr,
                                              unsigned short* __restrict__ Ktf) {
  const int n = blockIdx.x;
  const int t = threadIdx.x;
  __shared__ float kl[16384];               // 64 KB: K[n] swizzled (d-quad ^ j&7)
  const float* src = Kr + (size_t)n * 16384;
#pragma unroll
  for (int c = 0; c < 16; ++c) {
    const int idx = (c * 256 + t) * 4;      // linear dword idx = j*512 + k*32 + d
    const int jj  = idx >> 9;
    const int sidx = (idx & ~28) | (((((idx >> 2) & 7) ^ (jj & 7))) << 2);
    *(float4*)&kl[sidx] = *(const float4*)(src + idx);
  }
  __syncthreads();
  unsigned short* dst = Ktf + (size_t)n * 16384;
#pragma unroll
  for (int c = 0; c < 8; ++c) {
    const int chunk = c * 256 + t;          // (d, lane)
    const int d = chunk >> 6, lane = chunk & 63;
    const int j = lane & 31, khi = lane >> 5;
    const int dsw = ((((d >> 2) ^ (j & 7)) << 2)) | (d & 3);
    unsigned short u8[8];
#pragma unroll
    for (int i = 0; i < 8; ++i)
      u8[i] = f2bf(kl[j * 512 + (khi * 8 + i) * 32 + dsw]);
    uint4 o;
    o.x = u8[0] | ((unsigned)u8[1] << 16);
    o.y = u8[2] | ((unsigned)u8[3] << 16);
    o.z = u8[4] | ((unsigned)u8[5] << 16);
    o.w = u8[6] | ((unsigned)u8[7] << 16);
    *(uint4*)(dst + (size_t)chunk * 8) = o;
  }
}

// x[b][n][k] fp32 -> xtf[bh][n][lane][i] bf16; A-frag: row b = lane&31, k = (lane>>5)*8+i
__global__ __launch_bounds__(256) void conv_x(const float* __restrict__ x,
                                              unsigned short* __restrict__ xtf) {
  const int g = blockIdx.x * 256 + threadIdx.x;   // 262144 chunks
  const int bh = g >> 17, rem = g & 131071;
  const int n = rem >> 6, lane = rem & 63;
  const int b = bh * 32 + (lane & 31), khi = lane >> 5;
  const float* src = x + ((size_t)b * NIN + n) * DIN + khi * 8;
  unsigned short u8[8];
#pragma unroll
  for (int i = 0; i < 8; ++i) u8[i] = f2bf(src[i]);
  uint4 o;
  o.x = u8[0] | ((unsigned)u8[1] << 16);
  o.y = u8[2] | ((unsigned)u8[3] << 16);
  o.z = u8[4] | ((unsigned)u8[5] << 16);
  o.w = u8[6] | ((unsigned)u8[7] << 16);
  *(uint4*)(xtf + (size_t)g * 8) = o;
}

// MODE 0: C = 1/32 uniform. MODE 1: Blog = U.V (write), C = softmax.
// MODE 2: l = Blog + U.V (read), C = softmax.
// Block: 1024 thr = 16 waves; wave w owns d in {2w, 2w+1}. Grid (256 nt, 2 bh).
// C/D layout (verified r3): col j = lane&31, row b = (r&3) + 4*(lane>>5) + 8*(r>>2).
template<int MODE>
__global__ __launch_bounds__(1024, 4) void caps_mfma(
    const unsigned short* __restrict__ Ktf, const unsigned short* __restrict__ xtf,
    const float* __restrict__ Vin, float* __restrict__ Blog,
    float* __restrict__ Spart)
{
  const int tid = threadIdx.x;
  const int w = tid >> 6, lane = tid & 63;
  const int j = lane & 31, hi = lane >> 5;
  const int nt = blockIdx.x, bh = blockIdx.y;
  const int n0 = nt * NTILE;

  __shared__ float Ds[2][32][32];   // dot accumulators (atomic), zero-recycled
  __shared__ float Cs[2][32][32];   // softmax coefficients

  float sacc[16][2];
#pragma unroll
  for (int r = 0; r < 16; ++r) { sacc[r][0] = 0.f; sacc[r][1] = 0.f; }

  float vreg[16][2];                // V[b(r,hi)][j][2w+dd], loaded once per block
  if (MODE != 0) {
#pragma unroll
    for (int r = 0; r < 16; ++r) {
      const int b = (r & 3) + 4 * hi + 8 * (r >> 2);
      const float2 v2 = *(const float2*)(Vin + (((size_t)(bh * 32 + b) * 32 + j) * 32 + 2 * w));
      vreg[r][0] = v2.x; vreg[r][1] = v2.y;
    }
    // zero Ds (d_ws is poisoned 0xAA)
    ((float*)Ds)[tid]        = 0.f;
    ((float*)Ds)[tid + 1024] = 0.f;
    __syncthreads();
  }

  const int bc = tid >> 5;          // phase-C b (0..31)
  const int jc = tid & 31;          // phase-C j

  for (int np = 0; np < NTILE / 2; ++np) {
    const int nbase = n0 + np * 2;
    s16x8 a0, a1;

    // ---- phase A: MFMA -> dot partials -> Ds atomic add --------------------
#pragma unroll
    for (int nn = 0; nn < 2; ++nn) {
      const int n = nbase + nn;
      const s16x8 a = *(const s16x8*)(xtf + (((size_t)bh * NIN + n) * 64 + lane) * 8);
      if (nn == 0) a0 = a; else a1 = a;
      if (MODE == 0) {
#pragma unroll
        for (int dd = 0; dd < 2; ++dd) {
          const s16x8 bf = *(const s16x8*)(Ktf + (((size_t)n * 32 + (2 * w + dd)) * 64 + lane) * 8);
          f32x16 z;
#pragma unroll
          for (int q = 0; q < 16; ++q) z[q] = 0.f;
          const f32x16 u = __builtin_amdgcn_mfma_f32_32x32x16_bf16(a, bf, z, 0, 0, 0);
#pragma unroll
          for (int r = 0; r < 16; ++r) sacc[r][dd] = fmaf(0.03125f, u[r], sacc[r][dd]);
        }
      } else {
        float pd[16];
#pragma unroll
        for (int r = 0; r < 16; ++r) pd[r] = 0.f;
#pragma unroll
        for (int dd = 0; dd < 2; ++dd) {
          const s16x8 bf = *(const s16x8*)(Ktf + (((size_t)n * 32 + (2 * w + dd)) * 64 + lane) * 8);
          f32x16 z;
#pragma unroll
          for (int q = 0; q < 16; ++q) z[q] = 0.f;
          const f32x16 u = __builtin_amdgcn_mfma_f32_32x32x16_bf16(a, bf, z, 0, 0, 0);
#pragma unroll
          for (int r = 0; r < 16; ++r) pd[r] = fmaf(u[r], vreg[r][dd], pd[r]);
        }
#pragma unroll
        for (int r = 0; r < 16; ++r) {
          const int b = (r & 3) + 4 * hi + 8 * (r >> 2);
          atomicAdd(&Ds[nn][b][j], pd[r]);
        }
      }
    }
    if (MODE == 0) continue;

    __syncthreads();

    // ---- phase C: read own slot, softmax over j (no max-sub), write Cs -----
    {
      float l0 = Ds[0][bc][jc];
      float l1 = Ds[1][bc][jc];
      const size_t bi0 = (((size_t)(bh * 32 + bc) * NIN) + nbase) * 32 + jc;
      const size_t bi1 = bi0 + 32;
      if (MODE == 1) { Blog[bi0] = l0; Blog[bi1] = l1; }
      else           { l0 += Blog[bi0]; l1 += Blog[bi1]; }
      const float e0 = __expf(l0), e1 = __expf(l1);
      float s0 = e0, s1 = e1;
#pragma unroll
      for (int m = 16; m >= 1; m >>= 1) {
        s0 += __shfl_xor(s0, m, 64);
        s1 += __shfl_xor(s1, m, 64);
      }
      Cs[0][bc][jc] = __fdividef(e0, s0);
      Cs[1][bc][jc] = __fdividef(e1, s1);
      Ds[0][bc][jc] = 0.f;            // recycle own slot for next pair
      Ds[1][bc][jc] = 0.f;
    }
    __syncthreads();

    // ---- phase E: recompute MFMA (free), S += C * U ------------------------
#pragma unroll
    for (int nn = 0; nn < 2; ++nn) {
      const int n = nbase + nn;
      const s16x8 a = (nn == 0) ? a0 : a1;
      float c[16];
#pragma unroll
      for (int r = 0; r < 16; ++r) {
        const int b = (r & 3) + 4 * hi + 8 * (r >> 2);
        c[r] = Cs[nn][b][j];
      }
#pragma unroll
      for (int dd = 0; dd < 2; ++dd) {
        const s16x8 bf = *(const s16x8*)(Ktf + (((size_t)n * 32 + (2 * w + dd)) * 64 + lane) * 8);
        f32x16 z;
#pragma unroll
        for (int q = 0; q < 16; ++q) z[q] = 0.f;
        const f32x16 u = __builtin_amdgcn_mfma_f32_32x32x16_bf16(a, bf, z, 0, 0, 0);
#pragma unroll
        for (int r = 0; r < 16; ++r) sacc[r][dd] = fmaf(c[r], u[r], sacc[r][dd]);
      }
    }
  }

  // write per-block partial S: Spart[bh*NB+nt][b][j][d]
  float* Sp = Spart + (size_t)(bh * NB + nt) * 32768;
#pragma unroll
  for (int r = 0; r < 16; ++r) {
    const int b = (r & 3) + 4 * hi + 8 * (r >> 2);
    *(float2*)(Sp + ((size_t)b * 32 + j) * 32 + 2 * w) = make_float2(sacc[r][0], sacc[r][1]);
  }
}

// stage 1: 16-way split of the 512-tile sum; coalesced. 1M threads.
__global__ __launch_bounds__(256) void reduce_s1(const float* __restrict__ Spart,
                                                 float* __restrict__ Spart2) {
  const int g = blockIdx.x * 256 + threadIdx.x;   // [p][bh][ei]
  const int e = g & 65535, p = g >> 16;
  const int bh = e >> 15, ei = e & 32767;
  const float* base = Spart + ((size_t)(bh * NB + p * 16)) * 32768 + ei;
  float s = 0.f;
#pragma unroll
  for (int i = 0; i < 16; ++i) s += base[(size_t)i * 32768];
  Spart2[(size_t)p * 65536 + e] = s;
}

// stage 2: finish sum (16 partials), squash over d (= lane bits 0..4), write V.
__global__ __launch_bounds__(256) void reduce_s2(const float* __restrict__ Spart2,
                                                 float* __restrict__ Vout) {
  const int t = blockIdx.x * 256 + threadIdx.x;   // [b][j][d]
  float s = 0.f;
#pragma unroll
  for (int p = 0; p < 16; ++p) s += Spart2[(size_t)p * 65536 + t];
  float sq = s * s;
#pragma unroll
  for (int m = 16; m >= 1; m >>= 1) sq += __shfl_xor(sq, m, 64);
  Vout[t] = s * (sq / (1.0f + sq)) * rsqrtf(sq + 1e-8f);
}

extern "C" void kernel_launch(void* const* d_in, const int* in_sizes, int n_in,
                              void* d_out, int out_size, void* d_ws, size_t ws_size,
                              hipStream_t stream) {
  const float* x  = (const float*)d_in[0];
  const float* Kr = (const float*)d_in[1];
  float* ws = (float*)d_ws;
  float* Blog   = ws + WS_BLOG;
  float* Spart  = ws + WS_SPART;
  float* Spart2 = ws + WS_SPART2;
  float* V      = ws + WS_V;
  unsigned short* Ktf = (unsigned short*)(ws + WS_KTF);
  unsigned short* xtf = (unsigned short*)(ws + WS_XTF);
  float* out = (float*)d_out;

  conv_k<<<NIN, 256, 0, stream>>>(Kr, Ktf);
  conv_x<<<1024, 256, 0, stream>>>(x, xtf);

  const dim3 g(NB, 2), blk(1024);
  caps_mfma<0><<<g, blk, 0, stream>>>(Ktf, xtf, nullptr, Blog, Spart);
  reduce_s1<<<4096, 256, 0, stream>>>(Spart, Spart2);
  reduce_s2<<<256, 256, 0, stream>>>(Spart2, V);
  caps_mfma<1><<<g, blk, 0, stream>>>(Ktf, xtf, V, Blog, Spart);
  reduce_s1<<<4096, 256, 0, stream>>>(Spart, Spart2);
  reduce_s2<<<256, 256, 0, stream>>>(Spart2, V);
  caps_mfma<2><<<g, blk, 0, stream>>>(Ktf, xtf, V, Blog, Spart);
  reduce_s1<<<4096, 256, 0, stream>>>(Spart, Spart2);
  reduce_s2<<<256, 256, 0, stream>>>(Spart2, out);
}

// Round 5
// 360.353 us; speedup vs baseline: 3.4389x; 3.4389x over previous
//
#include <hip/hip_runtime.h>

// CapsNet dynamic routing via bf16 MFMA (v_mfma_f32_32x32x16_bf16).
// Shapes: x[64][2048][16], kernel[2048][32][16][32], out V[64][32][32], fp32 in/out.
//
// Round-5: round-3 structure (512 thr, 8 waves x 4 d, launch_bounds(512,2) -- do
// NOT tighten: round-4's (1024,4) capped VGPR at 128 and spilled to scratch,
// 226MB phantom writes, 6x slowdown) + next-n register prefetch + no-max
// softmax + two-stage reduce.

#define NIN   2048
#define DIN   16
#define NOUT  32
#define DOUT  32
#define NTILE 16
#define NB    (NIN/NTILE)   // 128

typedef __attribute__((ext_vector_type(8)))  short s16x8;
typedef __attribute__((ext_vector_type(16))) float f32x16;

// ws float offsets
#define WS_BLOG   0                        // 64*2048*32        = 4194304 f
#define WS_SPART  4194304                  // 256 * 32768       = 8388608 f
#define WS_SPART2 12582912                 // 8 * 65536         = 524288 f
#define WS_V      13107200                 // 65536 f
#define WS_KTF    13172736                 // 2048*32*64*8 bf16 = 16777216 f-equiv
#define WS_XTF    29949952                 // 2*2048*64*8 bf16  = 1048576 f-equiv
// total = 30,998,528 floats ~= 124 MB

__device__ __forceinline__ unsigned short f2bf(float f) {
  unsigned u = __float_as_uint(f);
  u = (u + 0x7fffu + ((u >> 16) & 1u)) >> 16;
  return (unsigned short)u;
}

// Repack kernel[n][j][k][d] fp32 -> Ktf[n][d][lane][i] bf16 via LDS transpose.
// B-fragment convention: col j = lane&31, k = (lane>>5)*8 + i  (same as A's).
__global__ __launch_bounds__(256) void conv_k(const float* __restrict__ Kr,
                                              unsigned short* __restrict__ Ktf) {
  const int n = blockIdx.x;
  const int t = threadIdx.x;
  __shared__ float kl[16384];               // 64 KB: K[n] swizzled (d-quad ^ j&7)
  const float* src = Kr + (size_t)n * 16384;
#pragma unroll
  for (int c = 0; c < 16; ++c) {
    const int idx = (c * 256 + t) * 4;      // linear dword idx = j*512 + k*32 + d
    const int jj  = idx >> 9;
    const int sidx = (idx & ~28) | (((((idx >> 2) & 7) ^ (jj & 7))) << 2);
    *(float4*)&kl[sidx] = *(const float4*)(src + idx);
  }
  __syncthreads();
  unsigned short* dst = Ktf + (size_t)n * 16384;
#pragma unroll
  for (int c = 0; c < 8; ++c) {
    const int chunk = c * 256 + t;          // (d, lane)
    const int d = chunk >> 6, lane = chunk & 63;
    const int j = lane & 31, khi = lane >> 5;
    const int dsw = ((((d >> 2) ^ (j & 7)) << 2)) | (d & 3);
    unsigned short u8[8];
#pragma unroll
    for (int i = 0; i < 8; ++i)
      u8[i] = f2bf(kl[j * 512 + (khi * 8 + i) * 32 + dsw]);
    uint4 o;
    o.x = u8[0] | ((unsigned)u8[1] << 16);
    o.y = u8[2] | ((unsigned)u8[3] << 16);
    o.z = u8[4] | ((unsigned)u8[5] << 16);
    o.w = u8[6] | ((unsigned)u8[7] << 16);
    *(uint4*)(dst + (size_t)chunk * 8) = o;
  }
}

// x[b][n][k] fp32 -> xtf[bh][n][lane][i] bf16; A-frag: row b = lane&31, k = (lane>>5)*8+i
__global__ __launch_bounds__(256) void conv_x(const float* __restrict__ x,
                                              unsigned short* __restrict__ xtf) {
  const int g = blockIdx.x * 256 + threadIdx.x;   // 262144 chunks
  const int bh = g >> 17, rem = g & 131071;
  const int n = rem >> 6, lane = rem & 63;
  const int b = bh * 32 + (lane & 31), khi = lane >> 5;
  const float* src = x + ((size_t)b * NIN + n) * DIN + khi * 8;
  unsigned short u8[8];
#pragma unroll
  for (int i = 0; i < 8; ++i) u8[i] = f2bf(src[i]);
  uint4 o;
  o.x = u8[0] | ((unsigned)u8[1] << 16);
  o.y = u8[2] | ((unsigned)u8[3] << 16);
  o.z = u8[4] | ((unsigned)u8[5] << 16);
  o.w = u8[6] | ((unsigned)u8[7] << 16);
  *(uint4*)(xtf + (size_t)g * 8) = o;
}

// MODE 0: C = 1/32 uniform. MODE 1: Blog = U.V (write), C = softmax.
// MODE 2: l = Blog + U.V (read), C = softmax.
// Block: 512 thr = 8 waves; wave w owns d in [4w, 4w+4). Grid (128 nt, 2 bh).
// C/D layout (verified): col j = lane&31, row b = (r&3) + 4*(lane>>5) + 8*(r>>2).
template<int MODE>
__global__ __launch_bounds__(512, 2) void caps_mfma(
    const unsigned short* __restrict__ Ktf, const unsigned short* __restrict__ xtf,
    const float* __restrict__ Vin, float* __restrict__ Blog,
    float* __restrict__ Spart)
{
  const int tid = threadIdx.x;
  const int w = tid >> 6, lane = tid & 63;
  const int j = lane & 31, hi = lane >> 5;
  const int nt = blockIdx.x, bh = blockIdx.y;
  const int n0 = nt * NTILE;

  __shared__ float Ds[8][32][32];   // per-wave partial dots [w][b][j]
  __shared__ float Cs[32][32];      // softmax coefficients [b][j]

  float sacc[16][4];
#pragma unroll
  for (int r = 0; r < 16; ++r)
#pragma unroll
    for (int dd = 0; dd < 4; ++dd) sacc[r][dd] = 0.f;

  float vreg[16][4];                // V[b(r,hi)][j][4w+dd], loaded once
  if (MODE != 0) {
#pragma unroll
    for (int r = 0; r < 16; ++r) {
      const int b = (r & 3) + 4 * hi + 8 * (r >> 2);
      const float4 v4 = *(const float4*)(Vin + (((size_t)(bh * 32 + b) * 32 + j) * 32 + w * 4));
      vreg[r][0] = v4.x; vreg[r][1] = v4.y; vreg[r][2] = v4.z; vreg[r][3] = v4.w;
    }
  }

  const int rb = tid >> 5;          // reduce-phase b0 (0..15); b1 = rb+16
  const int rj = tid & 31;

  // fragment pointers (stride per n: xtf 512 shorts, Ktf 16384 shorts)
  const unsigned short* xp = xtf + (((size_t)bh * NIN + n0) * 64 + lane) * 8;
  const unsigned short* kp = Ktf + (((size_t)n0 * 32 + w * 4) * 64 + lane) * 8;

  // preload n0 fragments
  s16x8 a = *(const s16x8*)xp;
  s16x8 bf[4];
#pragma unroll
  for (int dd = 0; dd < 4; ++dd) bf[dd] = *(const s16x8*)(kp + dd * 512);

#pragma unroll 1
  for (int nn = 0; nn < NTILE; ++nn) {
    const int n = n0 + nn;

    f32x16 u[4];
#pragma unroll
    for (int dd = 0; dd < 4; ++dd) {
      f32x16 z;
#pragma unroll
      for (int q = 0; q < 16; ++q) z[q] = 0.f;
      u[dd] = __builtin_amdgcn_mfma_f32_32x32x16_bf16(a, bf[dd], z, 0, 0, 0);
    }

    // prefetch n+1 fragments (issue BEFORE the barriers; latency hides under C/E)
    const int inc = (nn < NTILE - 1) ? 1 : 0;
    const s16x8 a2 = *(const s16x8*)(xp + inc * 512);
    s16x8 bf2[4];
#pragma unroll
    for (int dd = 0; dd < 4; ++dd)
      bf2[dd] = *(const s16x8*)(kp + inc * 16384 + dd * 512);
    xp += inc * 512;
    kp += inc * 16384;

    if (MODE == 0) {
#pragma unroll
      for (int r = 0; r < 16; ++r)
#pragma unroll
        for (int dd = 0; dd < 4; ++dd)
          sacc[r][dd] = fmaf(0.03125f, u[dd][r], sacc[r][dd]);
    } else {
      // per-wave partial dot over its 4 d's -> Ds[w][b][j]  (bank = j, conflict-free)
#pragma unroll
      for (int r = 0; r < 16; ++r) {
        const float pd = u[0][r] * vreg[r][0] + u[1][r] * vreg[r][1]
                       + u[2][r] * vreg[r][2] + u[3][r] * vreg[r][3];
        const int b = (r & 3) + 4 * hi + 8 * (r >> 2);
        Ds[w][b][j] = pd;
      }
      __syncthreads();
      // full dot = sum over 8 waves; Blog update; in-wave softmax over j (no max-sub:
      // |logit| <= ~6 across all 3 iters, exp safe in fp32, mathematically identical)
      float l0 = 0.f, l1 = 0.f;
#pragma unroll
      for (int ww = 0; ww < 8; ++ww) { l0 += Ds[ww][rb][rj]; l1 += Ds[ww][rb + 16][rj]; }
      const size_t bi0 = ((size_t)(bh * 32 + rb) * NIN + n) * 32 + rj;
      const size_t bi1 = ((size_t)(bh * 32 + rb + 16) * NIN + n) * 32 + rj;
      if (MODE == 1) { Blog[bi0] = l0; Blog[bi1] = l1; }
      else           { l0 += Blog[bi0]; l1 += Blog[bi1]; }
      const float e0 = __expf(l0), e1 = __expf(l1);
      float s0 = e0, s1 = e1;
#pragma unroll
      for (int mm = 16; mm >= 1; mm >>= 1) {
        s0 += __shfl_xor(s0, mm, 64);
        s1 += __shfl_xor(s1, mm, 64);
      }
      Cs[rb][rj]      = __fdividef(e0, s0);
      Cs[rb + 16][rj] = __fdividef(e1, s1);
      __syncthreads();
      // S += C * U   (Cs read: bank = j, conflict-free)
#pragma unroll
      for (int r = 0; r < 16; ++r) {
        const int b = (r & 3) + 4 * hi + 8 * (r >> 2);
        const float c = Cs[b][j];
#pragma unroll
        for (int dd = 0; dd < 4; ++dd) sacc[r][dd] = fmaf(c, u[dd][r], sacc[r][dd]);
      }
    }

    a = a2;
#pragma unroll
    for (int dd = 0; dd < 4; ++dd) bf[dd] = bf2[dd];
  }

  // write per-block partial S: Spart[bh*NB+nt][b][j][d]
  float* Sp = Spart + (size_t)(bh * NB + nt) * 32768;
#pragma unroll
  for (int r = 0; r < 16; ++r) {
    const int b = (r & 3) + 4 * hi + 8 * (r >> 2);
    *(float4*)(Sp + ((size_t)b * 32 + j) * 32 + w * 4) =
        make_float4(sacc[r][0], sacc[r][1], sacc[r][2], sacc[r][3]);
  }
}

// stage 1: 8 groups of 16 tiles each; coalesced. 524288 threads.
__global__ __launch_bounds__(256) void reduce_s1(const float* __restrict__ Spart,
                                                 float* __restrict__ Spart2) {
  const int g = blockIdx.x * 256 + threadIdx.x;   // [p][bh][ei]
  const int e = g & 65535, p = g >> 16;           // p = 0..7
  const int bh = e >> 15, ei = e & 32767;
  const float* base = Spart + ((size_t)(bh * NB + p * 16)) * 32768 + ei;
  float s = 0.f;
#pragma unroll
  for (int i = 0; i < 16; ++i) s += base[(size_t)i * 32768];
  Spart2[(size_t)p * 65536 + e] = s;
}

// stage 2: finish sum (8 partials), squash over d (= lane bits 0..4), write V.
__global__ __launch_bounds__(256) void reduce_s2(const float* __restrict__ Spart2,
                                                 float* __restrict__ Vout) {
  const int t = blockIdx.x * 256 + threadIdx.x;   // [b][j][d]
  float s = 0.f;
#pragma unroll
  for (int p = 0; p < 8; ++p) s += Spart2[(size_t)p * 65536 + t];
  float sq = s * s;
#pragma unroll
  for (int m = 16; m >= 1; m >>= 1) sq += __shfl_xor(sq, m, 64);
  Vout[t] = s * (sq / (1.0f + sq)) * rsqrtf(sq + 1e-8f);
}

extern "C" void kernel_launch(void* const* d_in, const int* in_sizes, int n_in,
                              void* d_out, int out_size, void* d_ws, size_t ws_size,
                              hipStream_t stream) {
  const float* x  = (const float*)d_in[0];
  const float* Kr = (const float*)d_in[1];
  float* ws = (float*)d_ws;
  float* Blog   = ws + WS_BLOG;
  float* Spart  = ws + WS_SPART;
  float* Spart2 = ws + WS_SPART2;
  float* V      = ws + WS_V;
  unsigned short* Ktf = (unsigned short*)(ws + WS_KTF);
  unsigned short* xtf = (unsigned short*)(ws + WS_XTF);
  float* out = (float*)d_out;

  conv_k<<<NIN, 256, 0, stream>>>(Kr, Ktf);
  conv_x<<<1024, 256, 0, stream>>>(x, xtf);

  const dim3 g(NB, 2), blk(512);
  caps_mfma<0><<<g, blk, 0, stream>>>(Ktf, xtf, nullptr, Blog, Spart);
  reduce_s1<<<2048, 256, 0, stream>>>(Spart, Spart2);
  reduce_s2<<<256, 256, 0, stream>>>(Spart2, V);
  caps_mfma<1><<<g, blk, 0, stream>>>(Ktf, xtf, V, Blog, Spart);
  reduce_s1<<<2048, 256, 0, stream>>>(Spart, Spart2);
  reduce_s2<<<256, 256, 0, stream>>>(Spart2, V);
  caps_mfma<2><<<g, blk, 0, stream>>>(Ktf, xtf, V, Blog, Spart);
  reduce_s1<<<2048, 256, 0, stream>>>(Spart, Spart2);
  reduce_s2<<<256, 256, 0, stream>>>(Spart2, out);
}